// Round 10
// baseline (744.233 us; speedup 1.0000x reference)
//
#include <hip/hip_runtime.h>

// HNM discriminative loss, MI355X — R13.
// predict (4,32,512,1024) f32, target (4,512,1024) i32 -> scalar f32.
// R13 = R12 with the fused-kernel job-map bug fixed (single variable).
// R12's mid-phase reduce assigned jobs 0..626 by blockIdx but the grid is
// 512: jobs 512..626 (96 channel sums + ALL 19 counts) never ran -> centers
// from poison -> absmax 35.5. Fix: every block does sum-job bid; blocks
// 0..95 also do sum-job bid+512; blocks 96..98 do the 19 count jobs
// per-wave (no divergent syncthreads). Everything else byte-identical:
// 512 blocks x 512 thr = 2/CU co-resident (barrier-safe), dual-parity hist
// phase A, ring-3 vmcnt(4) staging + ctrT[19][36] + per-pixel LDS atomics
// phase B, 16-striped device-scope barrier.

#define K_CLS 19
#define C_CH 32
#define HW_SHIFT 19            // H*W = 512*1024 = 2^19
#define EPSF 1e-12f
#define THEA_F 0.5f
#define TWO_DELTA 3.0f
#define MIN_PIX 20.0f
#define NBLK 512

// ---- ws float layout ------------------------------------------------------
#define OFF_PSUM 0              // [32 ch][16 slots][20] = 10240
#define OFF_PCNT 10240          // [512 blk][20] = 10240
#define OFF_RED  20480          // 608 sums + 19 counts (pad 640)
#define OFF_VRED 21120          // 38 reduced sq/pos (pad 64)
#define OFF_VPART 21184         // [512 blk][64]
#define OFF_BAR  53952          // 32 uints: 2 phases x 16 stripes

typedef const unsigned int __attribute__((address_space(1)))* GP;
typedef unsigned int __attribute__((address_space(3)))* LP;

__device__ __forceinline__ void atomAddF(float* p, float v) {
  unsafeAtomicAdd(p, v);
}

// LDS plan (bytes; union of phases, 78464 total):
//  phase A: histA f[0..9727]  histB f[9728..19455]  s_w f[19456..19615]
//  phase B: staging f[0..12287] ([8w][3ring][512])  ctrT f[12288..12971]
//           ([19][36])  bins f[12976..13295] ([8w][40])
#define SMEM_BYTES 78464

__device__ __forceinline__ void grid_barrier(unsigned* bar, int phase) {
  __syncthreads();
  if (threadIdx.x == 0) {
    __threadfence();
    __hip_atomic_fetch_add(&bar[phase * 16 + (blockIdx.x & 15)], 1u,
                           __ATOMIC_RELEASE, __HIP_MEMORY_SCOPE_AGENT);
    unsigned sum = 0;
    do {
      __builtin_amdgcn_s_sleep(8);
      sum = 0;
      for (int i = 0; i < 16; ++i)
        sum += __hip_atomic_load(&bar[phase * 16 + i],
                                 __ATOMIC_ACQUIRE, __HIP_MEMORY_SCOPE_AGENT);
    } while (sum < NBLK);
  }
  __syncthreads();
}

__global__ __launch_bounds__(512, 4) void k_fused(
    const float* __restrict__ pred, const int* __restrict__ tgt,
    float* __restrict__ ws, unsigned* __restrict__ bar)
{
  __shared__ __align__(16) char smem[SMEM_BYTES];
  float* smf = (float*)smem;
  const int t = threadIdx.x;
  const int w = t >> 6;
  const int lane = t & 63;
  const int bid = blockIdx.x;

  // ======== Phase A: (plane, slab) feature sums + distributed counts ======
  {
    const int plane = bid >> 2;            // 0..127 = n*32+ch
    const int slab  = bid & 3;             // 0..3 (128K px each)
    const int n_idx = plane >> 5;
    const int ch    = plane & 31;
    const float* pbase = pred + (((size_t)plane) << HW_SHIFT) + ((size_t)slab << 17);
    const int*   tbase = tgt  + (((size_t)n_idx) << HW_SHIFT) + ((size_t)slab << 17);

    float* colA = smf + w * (K_CLS * 64) + lane;
    float* colB = smf + 9728 + w * (K_CLS * 64) + lane;
#pragma unroll
    for (int k = 0; k < K_CLS; ++k) { colA[k << 6] = 0.f; colB[k << 6] = 0.f; }

    // counts: this block covers tgt sub-range [ch*4096, +4096) of its slab
    {
      const int* cb = tbase + ch * 4096;
      const int4 c0 = *reinterpret_cast<const int4*>(cb + t * 8);
      const int4 c1 = *reinterpret_cast<const int4*>(cb + t * 8 + 4);
      const int cs[8] = {c0.x, c0.y, c0.z, c0.w, c1.x, c1.y, c1.z, c1.w};
      float accc[K_CLS];
#pragma unroll
      for (int k = 0; k < K_CLS; ++k) accc[k] = 0.f;
#pragma unroll
      for (int j = 0; j < 8; ++j) {
#pragma unroll
        for (int k = 0; k < K_CLS; ++k) accc[k] += (cs[j] == k) ? 1.f : 0.f;
      }
#pragma unroll
      for (int k = 0; k < K_CLS; ++k) {
        float s = accc[k];
#pragma unroll
        for (int m = 1; m < 64; m <<= 1) s += __shfl_xor(s, m, 64);
        accc[k] = s;
      }
      float* s_w = smf + 19456;
#pragma unroll
      for (int k = 0; k < K_CLS; ++k)
        if (lane == k) s_w[w * 20 + k] = accc[k];
      __syncthreads();
      if (t < K_CLS) {
        float a = 0.f;
#pragma unroll
        for (int ww = 0; ww < 8; ++ww) a += s_w[ww * 20 + t];
        ws[OFF_PCNT + bid * 20 + t] = a;
      }
      __syncthreads();
    }

    // main loop: 64 iters x 4 px, dual-parity RMW chains
    float4 vA = *reinterpret_cast<const float4*>(pbase + t * 4);
    int4   cA = *reinterpret_cast<const int4*>(tbase + t * 4);
#pragma unroll 1
    for (int it = 0; it < 64; ++it) {
      float4 vB; int4 cB;
      if (it + 1 < 64) {
        vB = *reinterpret_cast<const float4*>(pbase + (it + 1) * 2048 + t * 4);
        cB = *reinterpret_cast<const int4*>(tbase + (it + 1) * 2048 + t * 4);
      }
      const int k0 = min((unsigned)cA.x, 18u), k1 = min((unsigned)cA.y, 18u);
      const int k2 = min((unsigned)cA.z, 18u), k3 = min((unsigned)cA.w, 18u);
      const float v0 = ((unsigned)cA.x < K_CLS) ? vA.x : 0.f;
      const float v1 = ((unsigned)cA.y < K_CLS) ? vA.y : 0.f;
      const float v2 = ((unsigned)cA.z < K_CLS) ? vA.z : 0.f;
      const float v3 = ((unsigned)cA.w < K_CLS) ? vA.w : 0.f;
      colA[k0 << 6] += v0;
      colB[k1 << 6] += v1;
      colA[k2 << 6] += v2;
      colB[k3 << 6] += v3;
      vA = vB; cA = cB;
    }

    // flush: own columns -> wave shfl -> cross-wave -> psum slot
    float acc[K_CLS];
#pragma unroll
    for (int k = 0; k < K_CLS; ++k) acc[k] = colA[k << 6] + colB[k << 6];
#pragma unroll
    for (int k = 0; k < K_CLS; ++k) {
      float s = acc[k];
#pragma unroll
      for (int m = 1; m < 64; m <<= 1) s += __shfl_xor(s, m, 64);
      acc[k] = s;
    }
    {
      float* s_w = smf + 19456;
#pragma unroll
      for (int k = 0; k < K_CLS; ++k)
        if (lane == k) s_w[w * 20 + k] = acc[k];
      __syncthreads();
      if (t < K_CLS) {
        float a = 0.f;
#pragma unroll
        for (int ww = 0; ww < 8; ++ww) a += s_w[ww * 20 + t];
        ws[OFF_PSUM + ch * 320 + (n_idx * 4 + slab) * 20 + t] = a;
      }
    }
  }

  // ======== Mid: barrier, distributed 627-way reduce on 512 blocks ========
  grid_barrier(bar, 0);

  {
    // every block: sum-job bid (0..511)
    const int ch = bid / K_CLS, k = bid - ch * K_CLS;
    if (t < 16) {
      float a = ws[OFF_PSUM + ch * 320 + t * 20 + k];
      a += __shfl_xor(a, 1, 64);
      a += __shfl_xor(a, 2, 64);
      a += __shfl_xor(a, 4, 64);
      a += __shfl_xor(a, 8, 64);
      if (t == 0) ws[OFF_RED + bid] = a;
    }
  }
  if (bid < 96) {
    // sum-jobs 512..607
    const int j = bid + 512;
    const int ch = j / K_CLS, k = j - ch * K_CLS;
    if (t < 16) {
      float a = ws[OFF_PSUM + ch * 320 + t * 20 + k];
      a += __shfl_xor(a, 1, 64);
      a += __shfl_xor(a, 2, 64);
      a += __shfl_xor(a, 4, 64);
      a += __shfl_xor(a, 8, 64);
      if (t == 0) ws[OFF_RED + j] = a;
    }
  } else if (bid < 99) {
    // count jobs 0..18, one per wave: k = (bid-96)*8 + w
    const int k = (bid - 96) * 8 + w;
    if (k < K_CLS) {
      float a = 0.f;
#pragma unroll
      for (int m = 0; m < 8; ++m)
        a += ws[OFF_PCNT + (lane + m * 64) * 20 + k];
#pragma unroll
      for (int m2 = 1; m2 < 64; m2 <<= 1) a += __shfl_xor(a, m2, 64);
      if (lane == 0) ws[OFF_RED + 608 + k] = a;
    }
  }

  grid_barrier(bar, 1);

  // ======== Phase B: variance pass (4096 px/block) ========================
  {
    float* ctrT = smf + 12288;            // [19][36] padded transpose
    float* bins = smf + 12976;            // [8 waves][40]: 19 sq + 19 pos
    for (int i = t; i < C_CH * K_CLS; i += 512) {
      const int c = i / K_CLS, s = i - c * K_CLS;
      ctrT[s * 36 + c] = ws[OFF_RED + i] / fmaxf(ws[OFF_RED + 608 + s], 1.f);
    }
    if (t < 320) bins[t] = 0.f;
    __syncthreads();

    const size_t pxb = (size_t)bid * 4096;
    const int n_idx = (int)(pxb >> HW_SHIFT);
    const int hw0 = (int)(pxb & ((1 << HW_SHIFT) - 1)) + w * 512;
    const int nC = n_idx * C_CH;

    int cls[8];
#pragma unroll
    for (int win = 0; win < 8; ++win)
      cls[win] = tgt[((size_t)n_idx << HW_SHIFT) + hw0 + win * 64 + lane];

#define ISSUE(sidx)                                                           \
    { const int win_ = (sidx) >> 2, q_ = (sidx) & 3, ring_ = (sidx) % 3;      \
      const int pw_ = hw0 + win_ * 64;                                        \
      _Pragma("unroll")                                                       \
      for (int j = 0; j < 2; ++j) {                                           \
        const int ch_ = q_ * 8 + j * 4 + (lane >> 4);                         \
        const float* gp = pred + (((size_t)(nC + ch_)) << HW_SHIFT)           \
                          + pw_ + (lane & 15) * 4;                            \
        __builtin_amdgcn_global_load_lds((GP)gp,                              \
            (LP)(smem + (w * 6144 + ring_ * 2048 + j * 1024)), 16, 0, 0);     \
      } }

    ISSUE(0)
    ISSUE(1)

#pragma unroll
    for (int win = 0; win < 8; ++win) {
      const int c0 = cls[win];
      const bool vld = (unsigned)c0 < K_CLS;
      const int sc = vld ? c0 : 0;
      float d2 = 0.f;
#pragma unroll
      for (int q = 0; q < 4; ++q) {
        const int sidx = win * 4 + q;
        if (sidx + 2 <= 31) ISSUE(sidx + 2)
        if (sidx <= 29)      { asm volatile("s_waitcnt vmcnt(4)" ::: "memory"); }
        else if (sidx == 30) { asm volatile("s_waitcnt vmcnt(2)" ::: "memory"); }
        else                 { asm volatile("s_waitcnt vmcnt(0)" ::: "memory"); }
        __builtin_amdgcn_sched_barrier(0);
        const int ring = sidx % 3;
        const float* stg = smf + w * 1536 + ring * 512;
        const float4 g0 = *reinterpret_cast<const float4*>(&ctrT[sc * 36 + q * 8]);
        const float4 g1 = *reinterpret_cast<const float4*>(&ctrT[sc * 36 + q * 8 + 4]);
        const float x0 = stg[0 * 64 + lane], x1 = stg[1 * 64 + lane];
        const float x2 = stg[2 * 64 + lane], x3 = stg[3 * 64 + lane];
        const float x4 = stg[4 * 64 + lane], x5 = stg[5 * 64 + lane];
        const float x6 = stg[6 * 64 + lane], x7 = stg[7 * 64 + lane];
        const float e0 = g0.x - x0, e1 = g0.y - x1, e2 = g0.z - x2, e3 = g0.w - x3;
        const float e4 = g1.x - x4, e5 = g1.y - x5, e6 = g1.z - x6, e7 = g1.w - x7;
        d2 = fmaf(e0, e0, d2); d2 = fmaf(e1, e1, d2);
        d2 = fmaf(e2, e2, d2); d2 = fmaf(e3, e3, d2);
        d2 = fmaf(e4, e4, d2); d2 = fmaf(e5, e5, d2);
        d2 = fmaf(e6, e6, d2); d2 = fmaf(e7, e7, d2);
      }
      const float r = sqrtf(d2 + EPSF) - THEA_F;
      if (vld && r > 0.f) {
        atomAddF(&bins[w * 40 + sc], r * r);        // per-PIXEL LDS atomic
        atomAddF(&bins[w * 40 + 20 + sc], 1.f);
      }
    }
#undef ISSUE

    __syncthreads();
    if (t < 2 * K_CLS) {
      const int slot = (t < K_CLS) ? t : (20 + (t - K_CLS));
      float a = 0.f;
#pragma unroll
      for (int ww = 0; ww < 8; ++ww) a += bins[ww * 40 + slot];
      ws[OFF_VPART + (size_t)bid * 64 + t] = a;
    }
  }
}

// ---- Pre-reduce sq/pos: 38 blocks ----------------------------------------
__global__ __launch_bounds__(256) void k_vred(float* __restrict__ ws)
{
  const int o = blockIdx.x;            // 0..37
  const int t = threadIdx.x;
  float a = 0.f;
#pragma unroll
  for (int r = 0; r < 2; ++r)
    a += ws[OFF_VPART + (size_t)(t + r * 256) * 64 + o];
#pragma unroll
  for (int m = 1; m < 64; m <<= 1) a += __shfl_xor(a, m, 64);
  __shared__ float s[4];
  if ((t & 63) == 0) s[t >> 6] = a;
  __syncthreads();
  if (t == 0) ws[OFF_VRED + o] = s[0] + s[1] + s[2] + s[3];
}

// ---- Finalize -------------------------------------------------------------
__global__ __launch_bounds__(1024) void k_final(
    float* __restrict__ ws, float* __restrict__ out)
{
  __shared__ float s_ctr[C_CH * K_CLS];
  __shared__ float s_valid[K_CLS];
  __shared__ float s_red[3];
  __shared__ float s_ncls;
  const int t = threadIdx.x;
  if (t < 3) s_red[t] = 0.f;
  if (t < K_CLS) s_valid[t] = (ws[OFF_RED + C_CH * K_CLS + t] > MIN_PIX) ? 1.f : 0.f;
  for (int i = t; i < C_CH * K_CLS; i += 1024) {
    const int k = i % K_CLS;
    s_ctr[i] = ws[OFF_RED + i] / fmaxf(ws[OFF_RED + C_CH * K_CLS + k], 1.f);
  }
  __syncthreads();

  if (t == 0) {
    float n = 0.f;
    for (int k = 0; k < K_CLS; ++k) n += s_valid[k];
    s_ncls = fmaxf(n, 1.f);
  }
  if (t < K_CLS && s_valid[t] > 0.f) {
    const float sq  = ws[OFF_VRED + t];
    const float pos = ws[OFF_VRED + K_CLS + t];
    atomAddF(&s_red[0], sq / fmaxf(pos, 1.f));
    float nn = 0.f;
#pragma unroll
    for (int ch = 0; ch < C_CH; ++ch) {
      const float cv = s_ctr[ch * K_CLS + t];
      nn = fmaf(cv, cv, nn);
    }
    atomAddF(&s_red[2], sqrtf(nn + EPSF));
  }
  if (t < K_CLS * K_CLS) {
    const int a = t / K_CLS, b = t - (t / K_CLS) * K_CLS;
    if (a != b && s_valid[a] > 0.f && s_valid[b] > 0.f) {
      float dd = 0.f;
#pragma unroll
      for (int ch = 0; ch < C_CH; ++ch) {
        const float df = s_ctr[ch * K_CLS + a] - s_ctr[ch * K_CLS + b];
        dd = fmaf(df, df, dd);
      }
      const float dist = sqrtf(dd + EPSF);
      const float d = fmaxf(TWO_DELTA - dist, 0.f);
      if (d > 0.f) atomAddF(&s_red[1], d * d);
    }
  }
  __syncthreads();
  if (t == 0) {
    const float n = s_ncls;
    out[0] = s_red[0] / n
           + s_red[1] / fmaxf(n * (n - 1.f), 1.f)
           + 0.001f * s_red[2] / n;
  }
}

extern "C" void kernel_launch(void* const* d_in, const int* in_sizes, int n_in,
                              void* d_out, int out_size, void* d_ws, size_t ws_size,
                              hipStream_t stream) {
  const float* pred = (const float*)d_in[0];
  const int*   tgt  = (const int*)d_in[1];
  float* ws  = (float*)d_ws;
  float* out = (float*)d_out;

  hipMemsetAsync((char*)d_ws + OFF_BAR * 4, 0, 32 * 4, stream);
  k_fused<<<NBLK, 512, 0, stream>>>(pred, tgt, ws,
                                    (unsigned*)((float*)d_ws + OFF_BAR));
  k_vred <<<2 * K_CLS, 256, 0, stream>>>(ws);
  k_final<<<1, 1024, 0, stream>>>(ws, out);
}

// Round 11
// 441.718 us; speedup vs baseline: 1.6849x; 1.6849x over previous
//
#include <hip/hip_runtime.h>

// HNM discriminative loss, MI355X — R14.
// predict (4,32,512,1024) f32, target (4,512,1024) i32 -> scalar f32.
// R14: R13's counters (VALU 4.7%, HBM 7.4%, occ 47%, all idle) kill the
// fused design — barrier forces 2 blk/CU on phase A (wants 8), phase B
// serialized by pinned sched_barrier + random-sc b128 gathers. Keep one
// insight: FETCH 278MB << 520MB issued -> L3 serves ~half the 2nd pred pass
// (applies to split kernels too). Revert to R11 split (436us); change ONLY
// k_var: algebraic |ctr-x|^2 = |x|^2 - 2 x.ctr + |ctr|^2. x streams
// global->VGPR coalesced (no staging/barriers/vmcnt); class-dependent reads
// become ds_bpermute register gathers (lane k holds ctr[c][k]) — 0.5
// conflict-free DS-op/px vs ~32 conflicted LDS reads/px. d2 clamped at 0
// (cancellation ~3e-4 abs; threshold 0.71). accum/reduce/final: R11 exact.

#define K_CLS 19
#define C_CH 32
#define HW_SHIFT 19            // H*W = 512*1024 = 2^19
#define HW_SIZE (1 << HW_SHIFT)
#define EPSF 1e-12f
#define THEA_F 0.5f
#define TWO_DELTA 3.0f
#define MIN_PIX 20.0f

// ---- ws float layout (no global atomics; every cell written before read) --
#define OFF_PSUM 0                       // [ch][64 slots][20] = 40960
#define OFF_PCNT 40960                   // [64 slots][20] = 1280
#define OFF_RED  42240                   // 608 sums + 19 counts (pad 640)
#define OFF_VRED 42880                   // 38 reduced sq/pos (pad 64)
#define OFF_VPART 42944                  // [2048 blk][64]: 19 sq + 19 pos
#define WS_FLOATS (OFF_VPART + 2048 * 64)

__device__ __forceinline__ void atomAddF(float* p, float v) {
  unsafeAtomicAdd(p, v);       // cold paths only
}

__device__ __forceinline__ float bperm(float v, int byteidx) {
  return __int_as_float(__builtin_amdgcn_ds_bpermute(byteidx, __float_as_int(v)));
}

// ---- Pass 1 (R11 exact): single-parity bank-per-lane histogram ------------
__global__ __launch_bounds__(256) void k_accum(
    const float* __restrict__ pred, const int* __restrict__ tgt,
    float* __restrict__ ws)
{
  __shared__ float sA[4][K_CLS][64];            // 19456 B -> 8 blocks/CU
  __shared__ float s_w[4][20];
  const int t = threadIdx.x;
  const int w = t >> 6;
  const int lane = t & 63;
  float* colA = &sA[w][0][lane];                // colA[k<<6] = bin k, bank l%32
#pragma unroll
  for (int k = 0; k < K_CLS; ++k) colA[k << 6] = 0.f;

  if (blockIdx.x < 2048) {
    const int plane = blockIdx.x >> 4;       // 0..127
    const int slab  = blockIdx.x & 15;       // 0..15
    const int n_idx = plane >> 5;
    const int ch    = plane & 31;
    const float* pbase = pred + (((size_t)plane) << HW_SHIFT) + ((size_t)slab << 15);
    const int*   tbase = tgt  + (((size_t)n_idx) << HW_SHIFT) + ((size_t)slab << 15);

    float4 vA = *reinterpret_cast<const float4*>(pbase + t * 4);
    int4   cA = *reinterpret_cast<const int4*>(tbase + t * 4);
#pragma unroll 1
    for (int it = 0; it < 32; ++it) {
      float4 vB; int4 cB;
      if (it + 1 < 32) {
        vB = *reinterpret_cast<const float4*>(pbase + (it + 1) * 1024 + t * 4);
        cB = *reinterpret_cast<const int4*>(tbase + (it + 1) * 1024 + t * 4);
      }
      const float x[4] = {vA.x, vA.y, vA.z, vA.w};
      const int   s[4] = {cA.x, cA.y, cA.z, cA.w};
      const int   k0 = min((unsigned)s[0], 18u), k1 = min((unsigned)s[1], 18u);
      const int   k2 = min((unsigned)s[2], 18u), k3 = min((unsigned)s[3], 18u);
      const float v0 = ((unsigned)s[0] < K_CLS) ? x[0] : 0.f;
      const float v1 = ((unsigned)s[1] < K_CLS) ? x[1] : 0.f;
      const float v2 = ((unsigned)s[2] < K_CLS) ? x[2] : 0.f;
      const float v3 = ((unsigned)s[3] < K_CLS) ? x[3] : 0.f;
      colA[k0 << 6] += v0;
      colA[k1 << 6] += v1;
      colA[k2 << 6] += v2;
      colA[k3 << 6] += v3;
      vA = vB; cA = cB;
    }

    float acc[K_CLS];
#pragma unroll
    for (int k = 0; k < K_CLS; ++k) acc[k] = colA[k << 6];
#pragma unroll
    for (int k = 0; k < K_CLS; ++k) {
      float s = acc[k];
#pragma unroll
      for (int m = 1; m < 64; m <<= 1) s += __shfl_xor(s, m, 64);
      acc[k] = s;
    }
#pragma unroll
    for (int k = 0; k < K_CLS; ++k)
      if (lane == k) s_w[w][k] = acc[k];       // static index: no scratch
    __syncthreads();
    if (t < K_CLS) {
      const int slot = n_idx * 16 + slab;      // 0..63
      ws[OFF_PSUM + ch * (64 * 20) + slot * 20 + t] =
          s_w[0][t] + s_w[1][t] + s_w[2][t] + s_w[3][t];
    }
  } else {
    const int idx = blockIdx.x - 2048;       // 0..63
    const int n_idx = idx >> 4;
    const int slab  = idx & 15;
    const int* tbase = tgt + (((size_t)n_idx) << HW_SHIFT) + ((size_t)slab << 15);

#pragma unroll 1
    for (int it = 0; it < 32; ++it) {
      const int4 c4 = *reinterpret_cast<const int4*>(tbase + it * 1024 + t * 4);
      const int s[4] = {c4.x, c4.y, c4.z, c4.w};
      const int k0 = min((unsigned)s[0], 18u), k1 = min((unsigned)s[1], 18u);
      const int k2 = min((unsigned)s[2], 18u), k3 = min((unsigned)s[3], 18u);
      colA[k0 << 6] += ((unsigned)s[0] < K_CLS) ? 1.f : 0.f;
      colA[k1 << 6] += ((unsigned)s[1] < K_CLS) ? 1.f : 0.f;
      colA[k2 << 6] += ((unsigned)s[2] < K_CLS) ? 1.f : 0.f;
      colA[k3 << 6] += ((unsigned)s[3] < K_CLS) ? 1.f : 0.f;
    }

    float acc[K_CLS];
#pragma unroll
    for (int k = 0; k < K_CLS; ++k) acc[k] = colA[k << 6];
#pragma unroll
    for (int k = 0; k < K_CLS; ++k) {
      float s = acc[k];
#pragma unroll
      for (int m = 1; m < 64; m <<= 1) s += __shfl_xor(s, m, 64);
      acc[k] = s;
    }
#pragma unroll
    for (int k = 0; k < K_CLS; ++k)
      if (lane == k) s_w[w][k] = acc[k];
    __syncthreads();
    if (t < K_CLS) {
      const int slot = n_idx * 16 + slab;
      ws[OFF_PCNT + slot * 20 + t] = s_w[0][t] + s_w[1][t] + s_w[2][t] + s_w[3][t];
    }
  }
}

// ---- Reduce: 627 one-wave blocks, lane = slot (R11 exact) ----------------
__global__ __launch_bounds__(64) void k_reduce(float* __restrict__ ws)
{
  const int o = blockIdx.x;            // 0..626
  const int lane = threadIdx.x;        // 0..63 = slot
  float a;
  if (o < C_CH * K_CLS) {
    const int ch = o / K_CLS, k = o - ch * K_CLS;
    a = ws[OFF_PSUM + ch * (64 * 20) + lane * 20 + k];
  } else {
    a = ws[OFF_PCNT + lane * 20 + (o - C_CH * K_CLS)];
  }
#pragma unroll
  for (int m = 1; m < 64; m <<= 1) a += __shfl_xor(a, m, 64);
  if (lane == 0) ws[OFF_RED + o] = a;
}

// ---- Pass 2 v6: algebraic d2 + register-ctr bpermute gather ---------------
// Block = 1024 px (4 waves x 256 thr x 4 px). x streams global->VGPR
// coalesced; ctr gathered via ds_bpermute from lane-resident registers.
__global__ __launch_bounds__(256) void k_var(
    const float* __restrict__ pred, const int* __restrict__ tgt,
    float* __restrict__ ws)
{
  __shared__ float s_red[640];
  __shared__ float s_w[4][40];
  const int t = threadIdx.x;
  const int w = t >> 6;
  const int lane = t & 63;

  for (int i = t; i < 627; i += 256) s_red[i] = ws[OFF_RED + i];
  __syncthreads();

  // lane k (k<19) holds ctr[c][k]; c2reg holds |ctr_k|^2
  const float invc = (lane < K_CLS) ? 1.f / fmaxf(s_red[608 + lane], 1.f) : 0.f;
  float ctrreg[C_CH];
  float c2reg = 0.f;
#pragma unroll
  for (int c = 0; c < C_CH; ++c) {
    ctrreg[c] = (lane < K_CLS) ? s_red[c * K_CLS + lane] * invc : 0.f;
    c2reg = fmaf(ctrreg[c], ctrreg[c], c2reg);
  }

  const size_t px0 = (size_t)blockIdx.x * 1024;
  const int n_idx = (int)(px0 >> HW_SHIFT);
  const int hw = (int)(px0 & (HW_SIZE - 1)) + t * 4;
  const float* pb = pred + (((size_t)(n_idx * C_CH)) << HW_SHIFT) + hw;

  const int4 c4 = *reinterpret_cast<const int4*>(tgt + ((size_t)n_idx << HW_SHIFT) + hw);
  const int cls[4] = {c4.x, c4.y, c4.z, c4.w};
  bool vl[4]; int sc[4]; int idx[4];
#pragma unroll
  for (int j = 0; j < 4; ++j) {
    vl[j] = (unsigned)cls[j] < K_CLS;
    sc[j] = vl[j] ? cls[j] : 0;
    idx[j] = sc[j] << 2;                  // bpermute byte index = lane*4
  }

  float dot[4] = {0.f, 0.f, 0.f, 0.f};
  float nrm[4] = {0.f, 0.f, 0.f, 0.f};
#pragma unroll
  for (int c = 0; c < C_CH; ++c) {        // full unroll: all indices static
    const float4 x = *reinterpret_cast<const float4*>(pb + ((size_t)c << HW_SHIFT));
    const float cv0 = bperm(ctrreg[c], idx[0]);
    const float cv1 = bperm(ctrreg[c], idx[1]);
    const float cv2 = bperm(ctrreg[c], idx[2]);
    const float cv3 = bperm(ctrreg[c], idx[3]);
    dot[0] = fmaf(x.x, cv0, dot[0]);  nrm[0] = fmaf(x.x, x.x, nrm[0]);
    dot[1] = fmaf(x.y, cv1, dot[1]);  nrm[1] = fmaf(x.y, x.y, nrm[1]);
    dot[2] = fmaf(x.z, cv2, dot[2]);  nrm[2] = fmaf(x.z, x.z, nrm[2]);
    dot[3] = fmaf(x.w, cv3, dot[3]);  nrm[3] = fmaf(x.w, x.w, nrm[3]);
  }

  float acc_sq[K_CLS], acc_pos[K_CLS];
#pragma unroll
  for (int k = 0; k < K_CLS; ++k) { acc_sq[k] = 0.f; acc_pos[k] = 0.f; }
#pragma unroll
  for (int j = 0; j < 4; ++j) {
    const float c2j = bperm(c2reg, idx[j]);
    const float d2 = fmaxf(nrm[j] - 2.f * dot[j] + c2j, 0.f);
    const float r = sqrtf(d2 + EPSF) - THEA_F;
    const bool act = vl[j] && (r > 0.f);
    const float rr = act ? r * r : 0.f;
    const float pp = act ? 1.f : 0.f;
#pragma unroll
    for (int k = 0; k < K_CLS; ++k) {
      const bool b = (sc[j] == k);
      acc_sq[k]  += b ? rr : 0.f;
      acc_pos[k] += b ? pp : 0.f;
    }
  }

  // wave shfl reduce -> 4-wave combine -> vpart
#pragma unroll
  for (int k = 0; k < K_CLS; ++k) {
    float a = acc_sq[k], b = acc_pos[k];
#pragma unroll
    for (int m = 1; m < 64; m <<= 1) {
      a += __shfl_xor(a, m, 64);
      b += __shfl_xor(b, m, 64);
    }
    acc_sq[k] = a; acc_pos[k] = b;
  }
#pragma unroll
  for (int k = 0; k < K_CLS; ++k)
    if (lane == k) { s_w[w][k] = acc_sq[k]; s_w[w][20 + k] = acc_pos[k]; }
  __syncthreads();
  if (t < K_CLS) {
    float* vp = ws + OFF_VPART + (size_t)blockIdx.x * 64;
    vp[t]         = s_w[0][t] + s_w[1][t] + s_w[2][t] + s_w[3][t];
    vp[K_CLS + t] = s_w[0][20 + t] + s_w[1][20 + t] + s_w[2][20 + t] + s_w[3][20 + t];
  }
}

// ---- Pre-reduce sq/pos: 38 blocks x 256 threads (8-deep: 2048 blocks) -----
__global__ __launch_bounds__(256) void k_vred(float* __restrict__ ws)
{
  const int o = blockIdx.x;            // 0..37 (sq: 0..18, pos: 19..37)
  const int t = threadIdx.x;
  float a = 0.f;
#pragma unroll
  for (int r = 0; r < 8; ++r)
    a += ws[OFF_VPART + (size_t)(t + r * 256) * 64 + o];
#pragma unroll
  for (int m = 1; m < 64; m <<= 1) a += __shfl_xor(a, m, 64);
  __shared__ float s[4];
  if ((t & 63) == 0) s[t >> 6] = a;
  __syncthreads();
  if (t == 0) ws[OFF_VRED + o] = s[0] + s[1] + s[2] + s[3];
}

// ---- Finalize (R11 exact) -------------------------------------------------
__global__ __launch_bounds__(1024) void k_final(
    float* __restrict__ ws, float* __restrict__ out)
{
  __shared__ float s_ctr[C_CH * K_CLS];
  __shared__ float s_valid[K_CLS];
  __shared__ float s_red[3];
  __shared__ float s_ncls;
  const int t = threadIdx.x;
  if (t < 3) s_red[t] = 0.f;
  if (t < K_CLS) s_valid[t] = (ws[OFF_RED + C_CH * K_CLS + t] > MIN_PIX) ? 1.f : 0.f;
  for (int i = t; i < C_CH * K_CLS; i += 1024) {
    const int k = i % K_CLS;
    s_ctr[i] = ws[OFF_RED + i] / fmaxf(ws[OFF_RED + C_CH * K_CLS + k], 1.f);
  }
  __syncthreads();

  if (t == 0) {
    float n = 0.f;
    for (int k = 0; k < K_CLS; ++k) n += s_valid[k];
    s_ncls = fmaxf(n, 1.f);
  }
  if (t < K_CLS && s_valid[t] > 0.f) {
    const float sq  = ws[OFF_VRED + t];
    const float pos = ws[OFF_VRED + K_CLS + t];
    atomAddF(&s_red[0], sq / fmaxf(pos, 1.f));
    float nn = 0.f;
#pragma unroll
    for (int ch = 0; ch < C_CH; ++ch) {
      const float cv = s_ctr[ch * K_CLS + t];
      nn = fmaf(cv, cv, nn);
    }
    atomAddF(&s_red[2], sqrtf(nn + EPSF));
  }
  if (t < K_CLS * K_CLS) {
    const int a = t / K_CLS, b = t - (t / K_CLS) * K_CLS;
    if (a != b && s_valid[a] > 0.f && s_valid[b] > 0.f) {
      float dd = 0.f;
#pragma unroll
      for (int ch = 0; ch < C_CH; ++ch) {
        const float df = s_ctr[ch * K_CLS + a] - s_ctr[ch * K_CLS + b];
        dd = fmaf(df, df, dd);
      }
      const float dist = sqrtf(dd + EPSF);
      const float d = fmaxf(TWO_DELTA - dist, 0.f);
      if (d > 0.f) atomAddF(&s_red[1], d * d);
    }
  }
  __syncthreads();
  if (t == 0) {
    const float n = s_ncls;
    out[0] = s_red[0] / n
           + s_red[1] / fmaxf(n * (n - 1.f), 1.f)
           + 0.001f * s_red[2] / n;
  }
}

extern "C" void kernel_launch(void* const* d_in, const int* in_sizes, int n_in,
                              void* d_out, int out_size, void* d_ws, size_t ws_size,
                              hipStream_t stream) {
  const float* pred = (const float*)d_in[0];
  const int*   tgt  = (const int*)d_in[1];
  float* ws  = (float*)d_ws;
  float* out = (float*)d_out;
  const int P = in_sizes[1];            // n*h*w = 2097152
  const int nBlocksVar = P / 1024;      // 2048

  k_accum <<<2048 + 64, 256, 0, stream>>>(pred, tgt, ws);  // 2048 sum + 64 count
  k_reduce<<<C_CH * K_CLS + K_CLS, 64, 0, stream>>>(ws);   // 627 one-wave blocks
  k_var   <<<nBlocksVar, 256, 0, stream>>>(pred, tgt, ws);
  k_vred  <<<2 * K_CLS, 256, 0, stream>>>(ws);             // 38 blocks
  k_final <<<1, 1024, 0, stream>>>(ws, out);
}